// Round 1
// baseline (384.428 us; speedup 1.0000x reference)
//
#include <hip/hip_runtime.h>

// SRU forward: u = x@W (only k=0,1 columns), f = sigmoid(u1+bias), scan
// c_t = (c_{t-1}-x~)*f + x~, h = tanh(c). Outputs: h (L,B,N) then c_final (B,N).
//
// ws layout: [0,64MB) A_bf16 (32768x1024), [64,68MB) Bp bf16 (2048x1024 B^T,
// cols interleaved n=2d+j), [68,196MB) U bf16 (32768x2048).

typedef __attribute__((ext_vector_type(8))) short short8;
typedef __attribute__((ext_vector_type(4))) float f32x4;

#define L_SEQ 2048
#define BATCH 16
#define NIN   1024
#define NOUT  1024
#define MROWS (L_SEQ * BATCH)  // 32768
#define NCOLS (2 * NOUT)       // 2048

__device__ __forceinline__ unsigned short f2bf(float f) {
  unsigned u = __float_as_uint(f);
  u += 0x7fffu + ((u >> 16) & 1u);  // round-to-nearest-even
  return (unsigned short)(u >> 16);
}
__device__ __forceinline__ float bf2f(unsigned short b) {
  return __uint_as_float(((unsigned)b) << 16);
}
__device__ __forceinline__ float sigmoidf_(float x) {
  return __builtin_amdgcn_rcpf(1.f + __expf(-x));
}
__device__ __forceinline__ float fast_tanh(float x) {
  float ax = fabsf(x);
  float t = __expf(-2.f * ax);                       // (0,1] -> no overflow
  float r = (1.f - t) * __builtin_amdgcn_rcpf(1.f + t);
  return copysignf(r, x);
}

#define GLL16(gptr, lptr)                                              \
  __builtin_amdgcn_global_load_lds(                                    \
      (const __attribute__((address_space(1))) void*)(gptr),           \
      (__attribute__((address_space(3))) void*)(lptr), 16, 0, 0)

// ---- 1. x fp32 -> bf16 --------------------------------------------------
__global__ __launch_bounds__(256) void cvt_x_k(const float* __restrict__ x,
                                               unsigned short* __restrict__ o) {
  size_t i = ((size_t)blockIdx.x * 256 + threadIdx.x) * 8;
  const float4* p = (const float4*)(x + i);
  float4 a = p[0], b = p[1];
  union { unsigned short s[8]; uint4 v; } r;
  r.s[0] = f2bf(a.x); r.s[1] = f2bf(a.y); r.s[2] = f2bf(a.z); r.s[3] = f2bf(a.w);
  r.s[4] = f2bf(b.x); r.s[5] = f2bf(b.y); r.s[6] = f2bf(b.z); r.s[7] = f2bf(b.w);
  *(uint4*)(o + i) = r.v;
}

// ---- 2. pack W columns {3d, 3d+1} into B^T (n=2d+j, row-major [N][K]) ---
__global__ __launch_bounds__(256) void pack_w_k(const float* __restrict__ W,
                                                unsigned short* __restrict__ Bp) {
  int tid = blockIdx.x * 256 + threadIdx.x;  // 0 .. 2M-1
  int k = tid & (NIN - 1);
  int n = tid >> 10;
  int col = 3 * (n >> 1) + (n & 1);
  Bp[tid] = f2bf(W[(size_t)k * (3 * NOUT) + col]);
}

// ---- 3. bf16 MFMA GEMM, 128x128 tile, BK=32, fused bias+sigmoid ---------
__global__ __launch_bounds__(256) void gemm_k(const unsigned short* __restrict__ A,
                                              const unsigned short* __restrict__ B,
                                              const float* __restrict__ bias,
                                              unsigned short* __restrict__ U) {
  __shared__ __align__(16) unsigned short As[128 * 32];
  __shared__ __align__(16) unsigned short Bs[128 * 32];
  const int K = NIN;
  int tid = threadIdx.x;
  int n0 = blockIdx.x * 128;
  int m0 = blockIdx.y * 128;
  int wave = tid >> 6;
  int lane = tid & 63;
  int wm = (wave >> 1) * 64;
  int wn = (wave & 1) * 64;
  int lr = lane & 15;
  int lk = (lane >> 4) * 8;

  f32x4 zero = {0.f, 0.f, 0.f, 0.f};
  f32x4 acc[4][4];
#pragma unroll
  for (int i = 0; i < 4; ++i)
#pragma unroll
    for (int j = 0; j < 4; ++j) acc[i][j] = zero;

  // staging: thread tid loads 16B chunk (row = tid>>2, slot = tid&3); LDS is
  // linear in lane order (wave-uniform base + lane*16) as global_load_lds needs.
  int srow = tid >> 2;
  int scol = (tid & 3) * 8;
  const unsigned short* gA = A + (size_t)(m0 + srow) * K + scol;
  const unsigned short* gB = B + (size_t)(n0 + srow) * K + scol;
  char* lA = (char*)As + (size_t)tid * 16;
  char* lB = (char*)Bs + (size_t)tid * 16;

  for (int kt = 0; kt < K; kt += 32) {
    GLL16(gA + kt, lA);
    GLL16(gA + (size_t)64 * K + kt, lA + 4096);
    GLL16(gB + kt, lB);
    GLL16(gB + (size_t)64 * K + kt, lB + 4096);
    __syncthreads();  // compiler emits vmcnt(0) drain before s_barrier
    short8 af[4], bf_[4];
#pragma unroll
    for (int i = 0; i < 4; ++i)
      af[i] = *(const short8*)&As[(wm + i * 16 + lr) * 32 + lk];
#pragma unroll
    for (int j = 0; j < 4; ++j)
      bf_[j] = *(const short8*)&Bs[(wn + j * 16 + lr) * 32 + lk];
#pragma unroll
    for (int i = 0; i < 4; ++i)
#pragma unroll
      for (int j = 0; j < 4; ++j)
        acc[i][j] = __builtin_amdgcn_mfma_f32_16x16x32_bf16(af[i], bf_[j],
                                                            acc[i][j], 0, 0, 0);
    __syncthreads();  // protect LDS before next stage overwrites
  }

  // epilogue: C/D mapping col = lane&15, row = (lane>>4)*4 + reg
  int mr = (lane >> 4) * 4;
  int nc = lane & 15;
#pragma unroll
  for (int i = 0; i < 4; ++i) {
#pragma unroll
    for (int j = 0; j < 4; ++j) {
      int n = n0 + wn + j * 16 + nc;
      float bsel = bias[n >> 1];
      bool isf = (n & 1);
#pragma unroll
      for (int r = 0; r < 4; ++r) {
        int m = m0 + wm + i * 16 + mr + r;
        float v = acc[i][j][r];
        if (isf) v = sigmoidf_(v + bsel);
        U[(size_t)m * NCOLS + n] = f2bf(v);
      }
    }
  }
}

// ---- 4. sequential SRU scan + tanh --------------------------------------
// one thread per (b,d); 256 blocks x 64 threads -> every CU gets one wave.
__global__ __launch_bounds__(64) void sru_scan_k(const unsigned int* __restrict__ U2,
                                                 const float* __restrict__ c0,
                                                 float* __restrict__ out) {
  int lane = threadIdx.x;
  int blk = blockIdx.x;                 // 0..255
  int b = blk >> 4;
  int d = ((blk & 15) << 6) + lane;
  float c = c0[(b << 10) + d];
  const unsigned int* up = U2 + (size_t)b * NOUT + d;  // uint = (x~, f) pair
  float* op = out + (size_t)b * NOUT + d;
  const size_t stride = (size_t)BATCH * NOUT;  // 16384 elems per t
  for (int t = 0; t < L_SEQ; t += 8) {
    unsigned int w[8];
#pragma unroll
    for (int j = 0; j < 8; ++j) w[j] = up[(size_t)(t + j) * stride];
#pragma unroll
    for (int j = 0; j < 8; ++j) {
      float xt = bf2f((unsigned short)(w[j] & 0xffffu));
      float f  = bf2f((unsigned short)(w[j] >> 16));
      c = (c - xt) * f + xt;
      op[(size_t)(t + j) * stride] = fast_tanh(c);
    }
  }
  out[(size_t)MROWS * NOUT + (b << 10) + d] = c;  // c_final
}

extern "C" void kernel_launch(void* const* d_in, const int* in_sizes, int n_in,
                              void* d_out, int out_size, void* d_ws, size_t ws_size,
                              hipStream_t stream) {
  const float* x    = (const float*)d_in[0];
  const float* c0   = (const float*)d_in[1];
  const float* W    = (const float*)d_in[2];
  const float* bias = (const float*)d_in[3];
  float* out = (float*)d_out;

  char* ws = (char*)d_ws;
  unsigned short* Abf = (unsigned short*)ws;                          // 64 MB
  unsigned short* Bp  = (unsigned short*)(ws + ((size_t)64 << 20));   // 4 MB
  unsigned short* U   = (unsigned short*)(ws + ((size_t)68 << 20));   // 128 MB

  cvt_x_k<<<MROWS * NIN / (256 * 8), 256, 0, stream>>>(x, Abf);
  pack_w_k<<<NCOLS * NIN / 256, 256, 0, stream>>>(W, Bp);
  dim3 ggrid(NCOLS / 128, MROWS / 128);  // (16, 256)
  gemm_k<<<ggrid, 256, 0, stream>>>(Abf, Bp, bias, U);
  sru_scan_k<<<256, 64, 0, stream>>>((const unsigned int*)U, c0, out);
}

// Round 2
// 301.194 us; speedup vs baseline: 1.2763x; 1.2763x over previous
//
#include <hip/hip_runtime.h>

// SRU forward: u = x@W (only k=0,1 columns), f = sigmoid(u1+bias), scan
// c_t = (c_{t-1}-x~)*f + x~, h = tanh(c). Outputs: h (L,B,N) then c_final (B,N).
//
// ws layout: [0,64MB) A_bf16 (32768x1024)  -- dead after gemm, reused:
//            [0,4MB) AV per-chunk affine (a,v) float2; [4,6MB) CS chunk-start c
//            [64,68MB) Bp bf16 (2048x1024 B^T, cols interleaved n=2d+j)
//            [68,196MB) U bf16 (32768x2048)

typedef __attribute__((ext_vector_type(8))) short short8;
typedef __attribute__((ext_vector_type(4))) float f32x4;

#define L_SEQ 2048
#define BATCH 16
#define NIN   1024
#define NOUT  1024
#define MROWS (L_SEQ * BATCH)  // 32768
#define NCOLS (2 * NOUT)       // 2048
#define ROWELEMS (BATCH * NOUT)  // 16384 (b,d) lanes
#define NCHUNK 32
#define CHLEN  64              // 2048 / 32

__device__ __forceinline__ unsigned short f2bf(float f) {
  unsigned u = __float_as_uint(f);
  u += 0x7fffu + ((u >> 16) & 1u);  // round-to-nearest-even
  return (unsigned short)(u >> 16);
}
__device__ __forceinline__ float bf2f(unsigned short b) {
  return __uint_as_float(((unsigned)b) << 16);
}
__device__ __forceinline__ float sigmoidf_(float x) {
  return __builtin_amdgcn_rcpf(1.f + __expf(-x));
}
__device__ __forceinline__ float fast_tanh(float x) {
  float ax = fabsf(x);
  float t = __expf(-2.f * ax);                       // (0,1] -> no overflow
  float r = (1.f - t) * __builtin_amdgcn_rcpf(1.f + t);
  return copysignf(r, x);
}

#define GLL16(gptr, lptr)                                              \
  __builtin_amdgcn_global_load_lds(                                    \
      (const __attribute__((address_space(1))) void*)(gptr),           \
      (__attribute__((address_space(3))) void*)(lptr), 16, 0, 0)

// ---- 1. x fp32 -> bf16 --------------------------------------------------
__global__ __launch_bounds__(256) void cvt_x_k(const float* __restrict__ x,
                                               unsigned short* __restrict__ o) {
  size_t i = ((size_t)blockIdx.x * 256 + threadIdx.x) * 8;
  const float4* p = (const float4*)(x + i);
  float4 a = p[0], b = p[1];
  union { unsigned short s[8]; uint4 v; } r;
  r.s[0] = f2bf(a.x); r.s[1] = f2bf(a.y); r.s[2] = f2bf(a.z); r.s[3] = f2bf(a.w);
  r.s[4] = f2bf(b.x); r.s[5] = f2bf(b.y); r.s[6] = f2bf(b.z); r.s[7] = f2bf(b.w);
  *(uint4*)(o + i) = r.v;
}

// ---- 2. pack W columns {3d, 3d+1} into B^T (n=2d+j, row-major [N][K]) ---
__global__ __launch_bounds__(256) void pack_w_k(const float* __restrict__ W,
                                                unsigned short* __restrict__ Bp) {
  int tid = blockIdx.x * 256 + threadIdx.x;  // 0 .. 2M-1
  int k = tid & (NIN - 1);
  int n = tid >> 10;
  int col = 3 * (n >> 1) + (n & 1);
  Bp[tid] = f2bf(W[(size_t)k * (3 * NOUT) + col]);
}

// ---- 3. bf16 MFMA GEMM, 128x128 tile, BK=32, fused bias+sigmoid ---------
// 1D grid of 4096, XCD-chunked swizzle: XCD x gets m-rows [32x, 32x+32).
__global__ __launch_bounds__(256) void gemm_k(const unsigned short* __restrict__ A,
                                              const unsigned short* __restrict__ B,
                                              const float* __restrict__ bias,
                                              unsigned short* __restrict__ U) {
  __shared__ __align__(16) unsigned short As[128 * 32];
  __shared__ __align__(16) unsigned short Bs[128 * 32];
  const int K = NIN;
  int tid = threadIdx.x;
  int bi = blockIdx.x;
  int t = (bi & 7) * 512 + (bi >> 3);   // bijective: 4096 % 8 == 0
  int n0 = (t & 15) << 7;
  int m0 = (t >> 4) << 7;
  int wave = tid >> 6;
  int lane = tid & 63;
  int wm = (wave >> 1) * 64;
  int wn = (wave & 1) * 64;
  int lr = lane & 15;
  int lk = (lane >> 4) * 8;

  f32x4 zero = {0.f, 0.f, 0.f, 0.f};
  f32x4 acc[4][4];
#pragma unroll
  for (int i = 0; i < 4; ++i)
#pragma unroll
    for (int j = 0; j < 4; ++j) acc[i][j] = zero;

  int srow = tid >> 2;
  int scol = (tid & 3) * 8;
  const unsigned short* gA = A + (size_t)(m0 + srow) * K + scol;
  const unsigned short* gB = B + (size_t)(n0 + srow) * K + scol;
  char* lA = (char*)As + (size_t)tid * 16;
  char* lB = (char*)Bs + (size_t)tid * 16;

  for (int kt = 0; kt < K; kt += 32) {
    GLL16(gA + kt, lA);
    GLL16(gA + (size_t)64 * K + kt, lA + 4096);
    GLL16(gB + kt, lB);
    GLL16(gB + (size_t)64 * K + kt, lB + 4096);
    __syncthreads();
    short8 af[4], bf_[4];
#pragma unroll
    for (int i = 0; i < 4; ++i)
      af[i] = *(const short8*)&As[(wm + i * 16 + lr) * 32 + lk];
#pragma unroll
    for (int j = 0; j < 4; ++j)
      bf_[j] = *(const short8*)&Bs[(wn + j * 16 + lr) * 32 + lk];
#pragma unroll
    for (int i = 0; i < 4; ++i)
#pragma unroll
      for (int j = 0; j < 4; ++j)
        acc[i][j] = __builtin_amdgcn_mfma_f32_16x16x32_bf16(af[i], bf_[j],
                                                            acc[i][j], 0, 0, 0);
    __syncthreads();
  }

  // epilogue: C/D mapping col = lane&15, row = (lane>>4)*4 + reg
  int mr = (lane >> 4) * 4;
  int nc = lane & 15;
#pragma unroll
  for (int i = 0; i < 4; ++i) {
#pragma unroll
    for (int j = 0; j < 4; ++j) {
      int n = n0 + wn + j * 16 + nc;
      float bsel = bias[n >> 1];
      bool isf = (n & 1);
#pragma unroll
      for (int r = 0; r < 4; ++r) {
        int m = m0 + wm + i * 16 + mr + r;
        float v = acc[i][j][r];
        if (isf) v = sigmoidf_(v + bsel);
        U[(size_t)m * NCOLS + n] = f2bf(v);
      }
    }
  }
}

// ---- 4a. per-chunk affine: c_end = a*c_start + v ------------------------
// block -> (b, chunk, dblk); lanes consecutive in d for coalescing.
__global__ __launch_bounds__(256) void scan_p1(const unsigned int* __restrict__ U2,
                                               float2* __restrict__ AV) {
  int tid = threadIdx.x;
  int bid = blockIdx.x;  // 2048 = 16 b * 32 chunk * 4 dblk
  int bd = ((bid >> 7) << 10) + ((bid & 3) << 8) + tid;  // b*1024 + d
  int chunk = (bid >> 2) & 31;
  const unsigned int* up = U2 + (size_t)chunk * CHLEN * ROWELEMS + bd;
  float a = 1.f, v = 0.f;
  for (int t0 = 0; t0 < CHLEN; t0 += 8) {
    unsigned int w[8];
#pragma unroll
    for (int j = 0; j < 8; ++j) w[j] = up[(size_t)(t0 + j) * ROWELEMS];
#pragma unroll
    for (int j = 0; j < 8; ++j) {
      float xt = bf2f((unsigned short)(w[j] & 0xffffu));
      float f  = bf2f((unsigned short)(w[j] >> 16));
      v = f * v + (1.f - f) * xt;
      a = a * f;
    }
  }
  AV[(size_t)chunk * ROWELEMS + bd] = make_float2(a, v);
}

// ---- 4b. scan chunk boundaries; emit c_final ----------------------------
__global__ __launch_bounds__(256) void scan_p2(const float2* __restrict__ AV,
                                               const float* __restrict__ c0,
                                               float* __restrict__ CS,
                                               float* __restrict__ out) {
  int bd = blockIdx.x * 256 + threadIdx.x;  // 64 blocks -> 16384
  float c = c0[bd];
  float2 av[NCHUNK];
#pragma unroll
  for (int k = 0; k < NCHUNK; ++k) av[k] = AV[(size_t)k * ROWELEMS + bd];
#pragma unroll
  for (int k = 0; k < NCHUNK; ++k) {
    CS[(size_t)k * ROWELEMS + bd] = c;
    c = av[k].x * c + av[k].y;
  }
  out[(size_t)MROWS * NOUT + bd] = c;  // c_final
}

// ---- 4c. replay each chunk exactly from corrected start; write h --------
__global__ __launch_bounds__(256) void scan_p3(const unsigned int* __restrict__ U2,
                                               const float* __restrict__ CS,
                                               float* __restrict__ out) {
  int tid = threadIdx.x;
  int bid = blockIdx.x;  // 2048
  int bd = ((bid >> 7) << 10) + ((bid & 3) << 8) + tid;
  int chunk = (bid >> 2) & 31;
  float c = CS[(size_t)chunk * ROWELEMS + bd];
  const unsigned int* up = U2 + (size_t)chunk * CHLEN * ROWELEMS + bd;
  float* op = out + (size_t)chunk * CHLEN * ROWELEMS + bd;
  for (int t0 = 0; t0 < CHLEN; t0 += 8) {
    unsigned int w[8];
#pragma unroll
    for (int j = 0; j < 8; ++j) w[j] = up[(size_t)(t0 + j) * ROWELEMS];
#pragma unroll
    for (int j = 0; j < 8; ++j) {
      float xt = bf2f((unsigned short)(w[j] & 0xffffu));
      float f  = bf2f((unsigned short)(w[j] >> 16));
      c = (c - xt) * f + xt;
      op[(size_t)(t0 + j) * ROWELEMS] = fast_tanh(c);
    }
  }
}

extern "C" void kernel_launch(void* const* d_in, const int* in_sizes, int n_in,
                              void* d_out, int out_size, void* d_ws, size_t ws_size,
                              hipStream_t stream) {
  const float* x    = (const float*)d_in[0];
  const float* c0   = (const float*)d_in[1];
  const float* W    = (const float*)d_in[2];
  const float* bias = (const float*)d_in[3];
  float* out = (float*)d_out;

  char* ws = (char*)d_ws;
  unsigned short* Abf = (unsigned short*)ws;                          // 64 MB
  unsigned short* Bp  = (unsigned short*)(ws + ((size_t)64 << 20));   // 4 MB
  unsigned short* U   = (unsigned short*)(ws + ((size_t)68 << 20));   // 128 MB
  // Abf region is dead after gemm_k -> reuse for scan scratch:
  float2* AV = (float2*)ws;                                           // 4 MB
  float*  CS = (float*)(ws + ((size_t)4 << 20));                      // 2 MB

  cvt_x_k<<<MROWS * NIN / (256 * 8), 256, 0, stream>>>(x, Abf);
  pack_w_k<<<NCOLS * NIN / 256, 256, 0, stream>>>(W, Bp);
  gemm_k<<<4096, 256, 0, stream>>>(Abf, Bp, bias, U);
  scan_p1<<<2048, 256, 0, stream>>>((const unsigned int*)U, AV);
  scan_p2<<<64, 256, 0, stream>>>(AV, c0, CS, out);
  scan_p3<<<2048, 256, 0, stream>>>((const unsigned int*)U, CS, out);
}

// Round 4
// 257.561 us; speedup vs baseline: 1.4926x; 1.1694x over previous
//
#include <hip/hip_runtime.h>

// SRU forward: u = x@W (only k=0,1 columns), f = sigmoid(u1+bias), scan
// c_t = (c_{t-1}-x~)*f + x~, h = tanh(c). Outputs: h (L,B,N) then c_final (B,N).
//
// GEMM: 256x256 tile, BK=64, 8-phase schedule (T2 swizzle + T3/T4 counted
// vmcnt + T5 setprio), 512 threads, 128 KiB LDS double-buffered.
// vmcnt placement: END of ph4/ph8 before the closing barrier (per-wave vmcnt
// + barrier = cross-wave availability; vmcnt at a phase START races).
//
// ws layout: [0,64MB) A_bf16 (32768x1024)  -- dead after gemm, reused:
//            [0,4MB) AV per-chunk affine; [4,6MB) CS chunk-start c
//            [64,68MB) Bp bf16 (2048x1024 B^T, cols interleaved n=2d+j)
//            [68,196MB) U bf16 (32768x2048)

typedef __attribute__((ext_vector_type(8))) short short8;
typedef __attribute__((ext_vector_type(4))) float f32x4;

#define L_SEQ 2048
#define BATCH 16
#define NIN   1024
#define NOUT  1024
#define MROWS (L_SEQ * BATCH)    // 32768
#define NCOLS (2 * NOUT)         // 2048
#define ROWELEMS (BATCH * NOUT)  // 16384
#define NCHUNK 32
#define CHLEN  64
#define NT 16                    // K-tiles of 64 (K=1024)

__device__ __forceinline__ unsigned short f2bf(float f) {
  unsigned u = __float_as_uint(f);
  u += 0x7fffu + ((u >> 16) & 1u);
  return (unsigned short)(u >> 16);
}
__device__ __forceinline__ float bf2f(unsigned short b) {
  return __uint_as_float(((unsigned)b) << 16);
}
__device__ __forceinline__ float sigmoidf_(float x) {
  return __builtin_amdgcn_rcpf(1.f + __expf(-x));
}
__device__ __forceinline__ float fast_tanh(float x) {
  float ax = fabsf(x);
  float t = __expf(-2.f * ax);
  float r = (1.f - t) * __builtin_amdgcn_rcpf(1.f + t);
  return copysignf(r, x);
}

#define GLL16(gptr, lptr)                                              \
  __builtin_amdgcn_global_load_lds(                                    \
      (const __attribute__((address_space(1))) void*)(gptr),           \
      (__attribute__((address_space(3))) void*)(lptr), 16, 0, 0)

// ---- 1. x fp32 -> bf16 --------------------------------------------------
__global__ __launch_bounds__(256) void cvt_x_k(const float* __restrict__ x,
                                               unsigned short* __restrict__ o) {
  size_t i = ((size_t)blockIdx.x * 256 + threadIdx.x) * 8;
  const float4* p = (const float4*)(x + i);
  float4 a = p[0], b = p[1];
  union { unsigned short s[8]; uint4 v; } r;
  r.s[0] = f2bf(a.x); r.s[1] = f2bf(a.y); r.s[2] = f2bf(a.z); r.s[3] = f2bf(a.w);
  r.s[4] = f2bf(b.x); r.s[5] = f2bf(b.y); r.s[6] = f2bf(b.z); r.s[7] = f2bf(b.w);
  *(uint4*)(o + i) = r.v;
}

// ---- 2. pack W columns {3d, 3d+1} into B^T (n=2d+j, row-major [N][K]) ---
__global__ __launch_bounds__(256) void pack_w_k(const float* __restrict__ W,
                                                unsigned short* __restrict__ Bp) {
  int tid = blockIdx.x * 256 + threadIdx.x;
  int k = tid & (NIN - 1);
  int n = tid >> 10;
  int col = 3 * (n >> 1) + (n & 1);
  Bp[tid] = f2bf(W[(size_t)k * (3 * NOUT) + col]);
}

// ---- 3. 256x256 8-phase MFMA GEMM ---------------------------------------
#define BARR __builtin_amdgcn_s_barrier()
#define SCHED0 __builtin_amdgcn_sched_barrier(0)
#define VMCNT(n) asm volatile("s_waitcnt vmcnt(" #n ")" ::: "memory")

// stage half-tile: 2 x global_load_lds per thread (128 rows x 64 cols bf16)
#define STAGE_A(bufc, ha, kt)                                                   \
  do {                                                                          \
    GLL16(pga##ha##0 + (kt) * 64, lds + (bufc) * 32768 + (ha) * 16384 + tid * 16);      \
    GLL16(pga##ha##1 + (kt) * 64, lds + (bufc) * 32768 + (ha) * 16384 + 8192 + tid * 16); \
  } while (0)
#define STAGE_B(bufc, hb, kt)                                                   \
  do {                                                                          \
    GLL16(pgb##hb##0 + (kt) * 64, lds + 65536 + (bufc) * 32768 + (hb) * 16384 + tid * 16); \
    GLL16(pgb##hb##1 + (kt) * 64, lds + 65536 + (bufc) * 32768 + (hb) * 16384 + 8192 + tid * 16); \
  } while (0)

#define LDA(DST, bufc, half)                                                    \
  _Pragma("unroll") for (int i = 0; i < 4; ++i) {                               \
    DST[i][0] = *(const short8*)(lds + (bufc) * 32768 + (half) * 16384 +        \
                                 (rowAb + i * 16) * 128 + colX0);               \
    DST[i][1] = *(const short8*)(lds + (bufc) * 32768 + (half) * 16384 +        \
                                 (rowAb + i * 16) * 128 + colX1);               \
  }
#define LDB(DST, bufc, half)                                                    \
  _Pragma("unroll") for (int j = 0; j < 2; ++j) {                               \
    DST[j][0] = *(const short8*)(lds + 65536 + (bufc) * 32768 + (half) * 16384 + \
                                 (rowBb + j * 16) * 128 + colX0);               \
    DST[j][1] = *(const short8*)(lds + 65536 + (bufc) * 32768 + (half) * 16384 + \
                                 (rowBb + j * 16) * 128 + colX1);               \
  }

#define MM(Q, AF, BF)                                                           \
  _Pragma("unroll") for (int i = 0; i < 4; ++i)                                 \
  _Pragma("unroll") for (int j = 0; j < 2; ++j) {                               \
    Q[i][j] = __builtin_amdgcn_mfma_f32_16x16x32_bf16(AF[i][0], BF[j][0], Q[i][j], 0, 0, 0); \
    Q[i][j] = __builtin_amdgcn_mfma_f32_16x16x32_bf16(AF[i][1], BF[j][1], Q[i][j], 0, 0, 0); \
  }

#define PH_TAIL(Q, AF, BF)                                                      \
  BARR;                                                                         \
  __builtin_amdgcn_s_setprio(1);                                                \
  MM(Q, AF, BF);                                                                \
  __builtin_amdgcn_s_setprio(0);                                                \
  BARR;                                                                         \
  SCHED0

// tail with counted vmcnt BEFORE the closing barrier: after the barrier, all
// waves' staging loads up to depth 4 have landed -> next phase may ds_read.
#define PH_TAILV(Q, AF, BF)                                                     \
  BARR;                                                                         \
  __builtin_amdgcn_s_setprio(1);                                                \
  MM(Q, AF, BF);                                                                \
  __builtin_amdgcn_s_setprio(0);                                                \
  VMCNT(4);                                                                     \
  BARR;                                                                         \
  SCHED0

#define EPI(Q, qm, qn)                                                          \
  do {                                                                          \
    _Pragma("unroll") for (int i = 0; i < 4; ++i)                               \
    _Pragma("unroll") for (int j = 0; j < 2; ++j) {                             \
      int n = n0 + (qn) * 128 + wn * 32 + j * 16 + nc;                          \
      float bsel = bias[n >> 1];                                                \
      _Pragma("unroll") for (int r = 0; r < 4; ++r) {                           \
        int m = m0 + (qm) * 128 + wm * 64 + i * 16 + mr + r;                    \
        float v = Q[i][j][r];                                                   \
        if (isf) v = sigmoidf_(v + bsel);                                       \
        U[(size_t)m * NCOLS + n] = f2bf(v);                                     \
      }                                                                         \
    }                                                                           \
  } while (0)

__global__ __launch_bounds__(512, 2) void gemm8_k(const unsigned short* __restrict__ A,
                                                  const unsigned short* __restrict__ B,
                                                  const float* __restrict__ bias,
                                                  unsigned short* __restrict__ U) {
  __shared__ __align__(16) char lds[131072];  // A: [buf][half][128][128B]; B at +64KB
  const int K = NIN;
  int tid = threadIdx.x;
  int wave = tid >> 6;
  int lane = tid & 63;
  int wm = wave >> 2;      // 0..1
  int wn = wave & 3;       // 0..3
  int lr = lane & 15;
  int hi = lane >> 4;

  // XCD-chunked swizzle (1024 % 8 == 0)
  int bi = blockIdx.x;
  int t = (bi & 7) * 128 + (bi >> 3);
  int n0 = (t & 7) << 8;
  int m0 = (t >> 3) << 8;

  // LDS read addressing (T2 swizzle: byte-col ^= (row&7)<<4)
  int rowAb = wm * 64 + lr;
  int rowBb = wn * 32 + lr;
  int swz = (lr & 7) << 4;
  int colX0 = (hi * 16) ^ swz;
  int colX1 = (64 + hi * 16) ^ swz;

  // staging source (inverse-swizzled global chunk, linear LDS dest)
  int row0 = tid >> 3;                 // 0..63
  int gch = (tid & 7) ^ (row0 & 7);
  const unsigned short* pga00 = A + (size_t)(m0 + row0) * K + gch * 8;
  const unsigned short* pga01 = pga00 + (size_t)64 * K;
  const unsigned short* pga10 = pga00 + (size_t)128 * K;
  const unsigned short* pga11 = pga00 + (size_t)192 * K;
  const unsigned short* pgb00 = B + (size_t)(n0 + row0) * K + gch * 8;
  const unsigned short* pgb01 = pgb00 + (size_t)64 * K;
  const unsigned short* pgb10 = pgb00 + (size_t)128 * K;
  const unsigned short* pgb11 = pgb00 + (size_t)192 * K;

  f32x4 zero = {0.f, 0.f, 0.f, 0.f};
  f32x4 acc00[4][2], acc01[4][2], acc11[4][2], acc10[4][2];
#pragma unroll
  for (int i = 0; i < 4; ++i)
#pragma unroll
    for (int j = 0; j < 2; ++j) {
      acc00[i][j] = zero; acc01[i][j] = zero;
      acc11[i][j] = zero; acc10[i][j] = zero;
    }

  short8 af[4][2], bq0[2][2], bq1[2][2];

  // prologue: tile0 complete + tile1 {A-half0, B-half1}; vmcnt->barrier order
  STAGE_A(0, 0, 0); STAGE_A(0, 1, 0); STAGE_B(0, 0, 0); STAGE_B(0, 1, 0);
  STAGE_A(1, 0, 1); STAGE_B(1, 1, 1);
  VMCNT(4);
  BARR;
  SCHED0;

  for (int it = 0; it < NT / 2; ++it) {
    int kt = it * 2;
    int k1 = kt + 1, k2 = (kt + 2) & (NT - 1), k3 = (kt + 3) & (NT - 1);
    // ph1: quad(0,0) of tile kt (buf0); stage (kt+1).B0 + (kt+1).A1 -> buf1
    STAGE_B(1, 0, k1); STAGE_A(1, 1, k1);
    LDA(af, 0, 0); LDB(bq0, 0, 0);
    PH_TAIL(acc00, af, bq0);
    // ph2: quad(0,1)
    LDB(bq1, 0, 1);
    PH_TAIL(acc01, af, bq1);
    // ph3: quad(1,1); stage (kt+2).A0 -> buf0 (buf0.A0 last ds_read ph1)
    STAGE_A(0, 0, k2);
    LDA(af, 0, 1);
    PH_TAIL(acc11, af, bq1);
    // ph4: quad(1,0); stage (kt+2).B1 (buf0.B1 last ds_read ph2)
    //      vmcnt(4) at tail: retires the 8 loads of tile kt+1 (buf1)
    STAGE_B(0, 1, k2);
    PH_TAILV(acc10, af, bq0);
    // ph5: quad(0,0) of tile kt+1 (buf1) -- available per ph4 vmcnt+barrier
    STAGE_A(0, 1, k2);
    LDA(af, 1, 0); LDB(bq0, 1, 0);
    PH_TAIL(acc00, af, bq0);
    // ph6: stage (kt+2).B0 (buf0.B0 last ds_read ph1)
    STAGE_B(0, 0, k2);
    LDB(bq1, 1, 1);
    PH_TAIL(acc01, af, bq1);
    // ph7: stage (kt+3).A0 -> buf1 (buf1.A0 last ds_read ph5)
    STAGE_A(1, 0, k3);
    LDA(af, 1, 1);
    PH_TAIL(acc11, af, bq1);
    // ph8: stage (kt+3).B1 (buf1.B1 last ds_read ph6)
    //      vmcnt(4) at tail: retires the 8 loads of tile kt+2 (buf0)
    STAGE_B(1, 1, k3);
    PH_TAILV(acc10, af, bq0);
  }
  VMCNT(0);  // drain wrap-staged loads before LDS reuse/exit

  // epilogue: C/D map col=lane&15, row=(lane>>4)*4+reg
  int mr = hi * 4;
  int nc = lane & 15;
  bool isf = nc & 1;
  EPI(acc00, 0, 0);
  EPI(acc01, 0, 1);
  EPI(acc11, 1, 1);
  EPI(acc10, 1, 0);
}

// ---- 4a. per-chunk affine: c_end = a*c_start + v ------------------------
__global__ __launch_bounds__(256) void scan_p1(const unsigned int* __restrict__ U2,
                                               float2* __restrict__ AV) {
  int tid = threadIdx.x;
  int bid = blockIdx.x;  // 2048 = 16 b * 32 chunk * 4 dblk
  int bd = ((bid >> 7) << 10) + ((bid & 3) << 8) + tid;
  int chunk = (bid >> 2) & 31;
  const unsigned int* up = U2 + (size_t)chunk * CHLEN * ROWELEMS + bd;
  float a = 1.f, v = 0.f;
  for (int t0 = 0; t0 < CHLEN; t0 += 8) {
    unsigned int w[8];
#pragma unroll
    for (int j = 0; j < 8; ++j) w[j] = up[(size_t)(t0 + j) * ROWELEMS];
#pragma unroll
    for (int j = 0; j < 8; ++j) {
      float xt = bf2f((unsigned short)(w[j] & 0xffffu));
      float f  = bf2f((unsigned short)(w[j] >> 16));
      v = f * v + (1.f - f) * xt;
      a = a * f;
    }
  }
  AV[(size_t)chunk * ROWELEMS + bd] = make_float2(a, v);
}

// ---- 4b. scan chunk boundaries; emit c_final ----------------------------
__global__ __launch_bounds__(256) void scan_p2(const float2* __restrict__ AV,
                                               const float* __restrict__ c0,
                                               float* __restrict__ CS,
                                               float* __restrict__ out) {
  int bd = blockIdx.x * 256 + threadIdx.x;
  float c = c0[bd];
  float2 av[NCHUNK];
#pragma unroll
  for (int k = 0; k < NCHUNK; ++k) av[k] = AV[(size_t)k * ROWELEMS + bd];
#pragma unroll
  for (int k = 0; k < NCHUNK; ++k) {
    CS[(size_t)k * ROWELEMS + bd] = c;
    c = av[k].x * c + av[k].y;
  }
  out[(size_t)MROWS * NOUT + bd] = c;
}

// ---- 4c. replay each chunk exactly from corrected start; write h --------
__global__ __launch_bounds__(256) void scan_p3(const unsigned int* __restrict__ U2,
                                               const float* __restrict__ CS,
                                               float* __restrict__ out) {
  int tid = threadIdx.x;
  int bid = blockIdx.x;
  int bd = ((bid >> 7) << 10) + ((bid & 3) << 8) + tid;
  int chunk = (bid >> 2) & 31;
  float c = CS[(size_t)chunk * ROWELEMS + bd];
  const unsigned int* up = U2 + (size_t)chunk * CHLEN * ROWELEMS + bd;
  float* op = out + (size_t)chunk * CHLEN * ROWELEMS + bd;
  for (int t0 = 0; t0 < CHLEN; t0 += 8) {
    unsigned int w[8];
#pragma unroll
    for (int j = 0; j < 8; ++j) w[j] = up[(size_t)(t0 + j) * ROWELEMS];
#pragma unroll
    for (int j = 0; j < 8; ++j) {
      float xt = bf2f((unsigned short)(w[j] & 0xffffu));
      float f  = bf2f((unsigned short)(w[j] >> 16));
      c = (c - xt) * f + xt;
      op[(size_t)(t0 + j) * ROWELEMS] = fast_tanh(c);
    }
  }
}

extern "C" void kernel_launch(void* const* d_in, const int* in_sizes, int n_in,
                              void* d_out, int out_size, void* d_ws, size_t ws_size,
                              hipStream_t stream) {
  const float* x    = (const float*)d_in[0];
  const float* c0   = (const float*)d_in[1];
  const float* W    = (const float*)d_in[2];
  const float* bias = (const float*)d_in[3];
  float* out = (float*)d_out;

  char* ws = (char*)d_ws;
  unsigned short* Abf = (unsigned short*)ws;                          // 64 MB
  unsigned short* Bp  = (unsigned short*)(ws + ((size_t)64 << 20));   // 4 MB
  unsigned short* U   = (unsigned short*)(ws + ((size_t)68 << 20));   // 128 MB
  float2* AV = (float2*)ws;                                           // 4 MB (after gemm)
  float*  CS = (float*)(ws + ((size_t)4 << 20));                      // 2 MB

  cvt_x_k<<<MROWS * NIN / (256 * 8), 256, 0, stream>>>(x, Abf);
  pack_w_k<<<NCOLS * NIN / 256, 256, 0, stream>>>(W, Bp);
  gemm8_k<<<1024, 512, 0, stream>>>(Abf, Bp, bias, U);
  scan_p1<<<2048, 256, 0, stream>>>((const unsigned int*)U, AV);
  scan_p2<<<64, 256, 0, stream>>>(AV, c0, CS, out);
  scan_p3<<<2048, 256, 0, stream>>>((const unsigned int*)U, CS, out);
}